// Round 5
// baseline (43971.066 us; speedup 1.0000x reference)
//
#include <hip/hip_runtime.h>
#include <hip/hip_bf16.h>

// DecoderRNN: 3-layer GRU, B=512, S=200, H=1024, V=100, teacher-forced scan.
// Persistent-kernel v5: 2 blocks/CU for inter-block latency hiding.
//  - 512 blocks of 256 threads (4 waves), tile 32M x 32N x 3 gates, 4-way
//    K-split across waves. LDS 64KB/block -> 2 blocks/CU co-resident
//    (__launch_bounds__(256,2)); while one block stalls on MALL-latency
//    bypass loads / barriers, the other computes.
//  - 2 grid barriers per step (was 3): X = L1(t) + OUT(t-1);
//    Y = L2(t) + L0(t+1).
//  - A (h-state): global_load_lds aux=17 (coherent bypass; == sc0 sc1 asm,
//    proven r2/r3). W: aux=0, L2-resident via XCD-pinned nb map.
//  - Double-buffered slabs (32KB), counted vmcnt(8); hprev in registers;
//    h stores write-through sc0 sc1; logits NT.

typedef __hip_bfloat16 bf16;
typedef __attribute__((ext_vector_type(8))) short short8;
typedef __attribute__((ext_vector_type(8))) unsigned short ushort8;
typedef __attribute__((ext_vector_type(16))) float f32x16;

#define B_ 512
#define S_ 200
#define H_ 1024
#define V_ 100
#define NBLK 512
#define BUFSZ 32768   // per slab buffer: A 8KB + W 24KB

__device__ __forceinline__ float bf2f(bf16 x) { return __bfloat162float(x); }
__device__ __forceinline__ float us2f(unsigned short u) {
  return __uint_as_float(((unsigned)u) << 16);
}

// ---------------------------------------------------------------------------
// Two-stage grid barrier over 512 blocks. Arrivals flags[0..511]; block 0
// wave 0 gathers (8 flags/lane), then publishes 8 padded release words
// (flags[512 + 32*g]); other blocks poll one word with thread 0. Monotonic
// gen; sticky ~20ms timeout -> fail fast (wrong answer, not hang).
// ---------------------------------------------------------------------------
__device__ __forceinline__ void gbar(unsigned* flags, unsigned gen,
                                     bool& dead) {
  __syncthreads();  // drains vmcnt/lgkm: write-through h stores visible
  const int tid = threadIdx.x;
  if (tid == 0)
    __hip_atomic_store(flags + blockIdx.x, gen, __ATOMIC_RELAXED,
                       __HIP_MEMORY_SCOPE_AGENT);
  if (blockIdx.x == 0) {
    if (tid < 64) {
      if (!dead) {
        unsigned long long t0 = __builtin_amdgcn_s_memrealtime();
        for (;;) {
          bool ok = true;
#pragma unroll
          for (int i = 0; i < 8; ++i)
            ok &= (__hip_atomic_load(flags + i * 64 + tid, __ATOMIC_RELAXED,
                                     __HIP_MEMORY_SCOPE_AGENT) >= gen);
          if (__all(ok)) break;
          __builtin_amdgcn_s_sleep(4);
          if (__builtin_amdgcn_s_memrealtime() - t0 > 2000000ULL) {  // ~20 ms
            dead = true;
            break;
          }
        }
      }
      if (tid < 8)  // release even if dead, so pollers advance
        __hip_atomic_store(flags + 512 + tid * 32, gen, __ATOMIC_RELAXED,
                           __HIP_MEMORY_SCOPE_AGENT);
    }
  } else if (tid == 0 && !dead) {
    unsigned* rel = flags + 512 + (blockIdx.x & 7) * 32;
    unsigned long long t0 = __builtin_amdgcn_s_memrealtime();
    while (__hip_atomic_load(rel, __ATOMIC_RELAXED,
                             __HIP_MEMORY_SCOPE_AGENT) < gen) {
      __builtin_amdgcn_s_sleep(8);
      if (__builtin_amdgcn_s_memrealtime() - t0 > 2500000ULL) {
        dead = true;
        break;
      }
    }
  }
  __syncthreads();
}

// ---------------------------------------------------------------------------
// Gates tile: one (mb,nb) 32x32x3 tile of h_l(t). 4 waves = 4-way K-split
// (wave q owns k-quarter q). Per 32-k-per-quarter slab: A granules 512
// ([q][row 0..31][slot 0..3], slot = kc ^ (row&3)), W granules 1536
// ([g][q][nl 0..31][slot 0..3]). Double-buffered, vmcnt(8).
// Epilogue on wave 0: 3-writer LDS reduction + GRU cell, register hprev.
// ---------------------------------------------------------------------------
template <int KTOT, bool L0T>
__device__ __forceinline__ void gates_tile(
    int mb, int nb,
    const bf16* __restrict__ A0,      // k in [0,1024)
    const bf16* __restrict__ A1,      // k in [1024,2048) (unused if KTOT=1024)
    const bf16* __restrict__ Wp,      // [3][1024][KTOT]
    const float* __restrict__ bias4,  // [4][1024]
    const float* __restrict__ table,  // [100][3072] (L0 only)
    const float* __restrict__ gprec,  // [512][3072] (L0 only)
    const int* __restrict__ inputs,   // [512][200]  (L0 only)
    int t,
    bf16* __restrict__ hout,          // h_l(t) [512][1024]
    unsigned (&hreg)[8],              // hprev bits, 2 bf16/word (wave 0 only)
    char* smem)
{
  constexpr int QK = KTOT / 4;       // k per quarter
  constexpr int NITER = KTOT / 128;  // 32 k per quarter per slab
  const int tid = threadIdx.x;
  const int lane = tid & 63;
  const int q = tid >> 6;  // wave = K-quarter

  __syncthreads();  // previous tile's red region fully consumed

  // ---- staging source pointers (8 granule-calls/thread); +64B per slab ----
  const char* gp[8];
#pragma unroll
  for (int c = 0; c < 8; ++c) {
    const int G = c * 256 + tid;
    if (c < 2) {  // A granule: G in [0,512): [qa][row][slot]
      int qa = G >> 7, r = (G >> 2) & 31, s = G & 3;
      int kc = s ^ (r & 3);
      int k = qa * QK + kc * 8;
      const bf16* src = (KTOT == 2048 && k >= 1024) ? A1 : A0;
      gp[c] = (const char*)(src + ((mb * 32 + r) * H_ + (k & 1023)));
    } else {      // W granule: Gb in [0,1536): [g][qb][nl][slot]
      int Gb = G - 512;
      int g = Gb >> 9, qb = (Gb >> 7) & 3, nl = (Gb >> 2) & 31, s = Gb & 3;
      int kc = s ^ (nl & 3);
      int k = qb * QK + kc * 8;
      gp[c] = (const char*)(Wp + ((g * 1024 + nb * 32 + nl) * KTOT + k));
    }
  }

#define STAGE(slot)                                                          \
  do {                                                                       \
    char* lbase = smem + (slot) * BUFSZ;                                     \
    _Pragma("unroll")                                                        \
    for (int c = 0; c < 8; ++c) {                                            \
      char* lp = lbase + (c * 256 + q * 64) * 16; /* + lane*16 by HW */      \
      if (c < 2)                                                             \
        __builtin_amdgcn_global_load_lds(                                    \
            (const __attribute__((address_space(1))) void*)gp[c],            \
            (__attribute__((address_space(3))) void*)lp, 16, 0, 17);         \
      else                                                                   \
        __builtin_amdgcn_global_load_lds(                                    \
            (const __attribute__((address_space(1))) void*)gp[c],            \
            (__attribute__((address_space(3))) void*)lp, 16, 0, 0);          \
      gp[c] += 64;                                                           \
    }                                                                        \
  } while (0)

  f32x16 accR, accZ, accN;
#pragma unroll
  for (int j = 0; j < 16; ++j) { accR[j] = 0.f; accZ[j] = 0.f; accN[j] = 0.f; }

  STAGE(0);
#pragma unroll
  for (int it = 0; it < NITER; ++it) {
    if (it + 1 < NITER) {
      STAGE((it + 1) & 1);
      asm volatile("s_waitcnt vmcnt(8)" ::: "memory");  // slab `it` landed
    } else {
      asm volatile("s_waitcnt vmcnt(0)" ::: "memory");
    }
    __builtin_amdgcn_sched_barrier(0);
    __builtin_amdgcn_s_barrier();
    __builtin_amdgcn_sched_barrier(0);
    const char* cb = smem + (it & 1) * BUFSZ;
#pragma unroll
    for (int kk = 0; kk < 2; ++kk) {
      const int rowA = lane & 31;
      const int kc = kk * 2 + (lane >> 5);
      short8 af = *(const short8*)(cb +
          (((q * 32 + rowA) * 4) + (kc ^ (rowA & 3))) * 16);
      const int nl = lane & 31;
      const int s2 = kc ^ (nl & 3);
      short8 bR = *(const short8*)(cb + 8192 +
          ((((0 * 4 + q) * 32 + nl) * 4) + s2) * 16);
      short8 bZ = *(const short8*)(cb + 8192 +
          ((((1 * 4 + q) * 32 + nl) * 4) + s2) * 16);
      short8 bN = *(const short8*)(cb + 8192 +
          ((((2 * 4 + q) * 32 + nl) * 4) + s2) * 16);
      accR = __builtin_amdgcn_mfma_f32_32x32x16_bf16(af, bR, accR, 0, 0, 0);
      accZ = __builtin_amdgcn_mfma_f32_32x32x16_bf16(af, bZ, accZ, 0, 0, 0);
      accN = __builtin_amdgcn_mfma_f32_32x32x16_bf16(af, bN, accN, 0, 0, 0);
    }
    asm volatile("s_waitcnt lgkmcnt(0)" ::: "memory");
    __builtin_amdgcn_sched_barrier(0);
    __builtin_amdgcn_s_barrier();   // all waves done reading buf(it&1)
    __builtin_amdgcn_sched_barrier(0);
  }
#undef STAGE
  __syncthreads();

  // ---- 4-way K-split reduction: waves 1..3 write partials (36KB) ----
  float* red = (float*)smem;
#define RED(w, g, j) red[(((w) * 3 + (g)) * 16 + (j)) * 64 + lane]
  if (q >= 1) {
#pragma unroll
    for (int j = 0; j < 16; ++j) {
      RED(q - 1, 0, j) = accR[j];
      RED(q - 1, 1, j) = accZ[j];
      RED(q - 1, 2, j) = accN[j];
    }
  }
  __syncthreads();
  if (q == 0) {
    const int nloc = lane & 31;
    const int n = nb * 32 + nloc;
    const float br = bias4[n], bz = bias4[1024 + n];
    const float bin = bias4[2048 + n], bhn = bias4[3072 + n];
#pragma unroll
    for (int j = 0; j < 16; ++j) {
      // C/D layout (32x32): col = lane&31, row = 4*(lane>>5)+(j&3)+8*(j>>2)
      int mloc = 4 * (lane >> 5) + (j & 3) + 8 * (j >> 2);
      int b = mb * 32 + mloc;
      float rt = accR[j] + RED(0, 0, j) + RED(1, 0, j) + RED(2, 0, j) + br;
      float zt = accZ[j] + RED(0, 1, j) + RED(1, 1, j) + RED(2, 1, j) + bz;
      float hn, npre;
      if (L0T) {
        int tok = (t == 0) ? 1 : inputs[b * S_ + (t - 1)];
        const float* tb = table + tok * 3072;
        const float* gpv = gprec + b * 3072;
        rt += tb[n] + gpv[n];
        zt += tb[1024 + n] + gpv[1024 + n];
        hn = accN[j] + RED(0, 2, j) + RED(1, 2, j) + RED(2, 2, j) + bhn;
        npre = tb[2048 + n] + gpv[2048 + n];  // i_n from table (incl bih0)
      } else {
        // quarters 0,1 = wih (i_n); quarters 2,3 = whh (h_n)
        npre = accN[j] + RED(0, 2, j) + bin;
        hn = RED(1, 2, j) + RED(2, 2, j) + bhn;
      }
      float r = 1.f / (1.f + __expf(-rt));
      float z = 1.f / (1.f + __expf(-zt));
      float nn = npre + r * hn;
      float e2 = __expf(2.f * nn);
      float th = 1.f - 2.f / (e2 + 1.f);  // tanh, inf-safe
      unsigned hpb = (hreg[j >> 1] >> ((j & 1) * 16)) & 0xffffu;
      float hp = us2f((unsigned short)hpb);
      float hv = (1.f - z) * th + z * hp;
      unsigned short hb =
          __builtin_bit_cast(unsigned short, __float2bfloat16(hv));
      if (j & 1)
        hreg[j >> 1] = (hreg[j >> 1] & 0x0000ffffu) | ((unsigned)hb << 16);
      else
        hreg[j >> 1] = (hreg[j >> 1] & 0xffff0000u) | (unsigned)hb;
      asm volatile("global_store_short %0, %1, off sc0 sc1"
                   :: "v"(hout + b * H_ + n), "v"((unsigned)hb) : "memory");
    }
  }
#undef RED
}

// ---------------------------------------------------------------------------
// OUT tile: 1 batch row per block (512 blocks = 512 rows).
// hs lives at smem+40960 (above the 36KB red region -> no sync needed vs
// a concurrently-running gates epilogue).
// ---------------------------------------------------------------------------
__device__ __forceinline__ void out_tile(
    int bid, const bf16* __restrict__ h2, const bf16* __restrict__ owTv,
    const float* __restrict__ logitde, float* __restrict__ out, int t,
    char* smem)
{
  float* hs = (float*)(smem + 40960);  // 1024 f32 = 4KB
  const int tid = threadIdx.x;
  const int b0 = bid;
  {
    const unsigned* pb = (const unsigned*)(h2 + b0 * H_) + tid;
    unsigned v0, v1;
    asm volatile(
        "global_load_dword %0, %2, off sc0 sc1\n\t"
        "global_load_dword %1, %2, off offset:1024 sc0 sc1\n\t"
        "s_waitcnt vmcnt(0)"
        : "=&v"(v0), "=&v"(v1)
        : "v"(pb)
        : "memory");
    hs[2 * tid] = us2f((unsigned short)(v0 & 0xffffu));
    hs[2 * tid + 1] = us2f((unsigned short)(v0 >> 16));
    hs[2 * (tid + 256)] = us2f((unsigned short)(v1 & 0xffffu));
    hs[2 * (tid + 256) + 1] = us2f((unsigned short)(v1 >> 16));
  }
  __syncthreads();
  if (tid < V_) {
    float acc = logitde[b0 * V_ + tid];
    const ushort8* row = (const ushort8*)(owTv + tid * H_);
#pragma unroll 4
    for (int k8 = 0; k8 < H_ / 8; ++k8) {
      ushort8 wv = row[k8];
#pragma unroll
      for (int i = 0; i < 8; ++i) acc += hs[k8 * 8 + i] * us2f(wv[i]);
    }
    __builtin_nontemporal_store(acc, &out[(b0 * S_ + t) * V_ + tid]);
  }
  __syncthreads();
}

// ---------------------------------------------------------------------------
// Persistent scan kernel: entire 200-step decode, 2 barriers/step.
//   X_t: L1(t) + OUT(t-1);  Y_t: L2(t) + L0(t+1).
// ---------------------------------------------------------------------------
__global__ __launch_bounds__(256, 2) void scan_kernel(
    const int* __restrict__ inputs,
    const bf16* __restrict__ Wp0, const bf16* __restrict__ Wp1,
    const bf16* __restrict__ Wp2, const float* __restrict__ bias4all,
    const float* __restrict__ table, const float* __restrict__ gprec0,
    const bf16* __restrict__ owTv, const float* __restrict__ logitde,
    bf16* __restrict__ hbuf, float* __restrict__ out,
    unsigned* __restrict__ flags)
{
  __shared__ char smem[65536];
  const int bid = blockIdx.x;
  const int tid = threadIdx.x;
  const int lane = tid & 63;
  const int q = tid >> 6;
  // XCD-pinned role map: XCD (bid%8) always owns the same 4 nb slices ->
  // its weight slice (3.93MB across layers) stays L2-resident.
  const int mb = bid >> 5;                           // 0..15 (32-row tiles)
  const int nb = (bid & 7) * 4 + ((bid >> 3) & 3);   // 0..31
  unsigned gen = 0;
  bool dead = false;

#define HBD(par, l) (hbuf + ((par) * 3 + (l)) * (B_ * H_))
  // ---- register-resident hprev init (all layers start at hinit) ----
  unsigned h0r[8], h1r[8], h2r[8];
  if (q == 0) {
#pragma unroll
    for (int jj = 0; jj < 8; ++jj) {
      int mloc = 4 * (lane >> 5) + ((2 * jj) & 3) + 8 * (jj >> 1);
      int b = mb * 32 + mloc;
      int n = nb * 32 + (lane & 31);
      unsigned lo = *(const unsigned short*)(HBD(0, 0) + b * H_ + n);
      unsigned hi = *(const unsigned short*)(HBD(0, 0) + (b + 1) * H_ + n);
      h0r[jj] = lo | (hi << 16);
      h1r[jj] = h0r[jj];
      h2r[jj] = h0r[jj];
    }
  }

  // Prologue: L0 step 0 (h_l(-1) lives in parity-0 buffers).
  gates_tile<1024, true>(mb, nb, HBD(0, 0), HBD(0, 0), Wp0, bias4all, table,
                         gprec0, inputs, 0, HBD(1, 0), h0r, smem);
  gbar(flags, ++gen, dead);

  for (int t = 0; t < S_; ++t) {
    const int pp = t & 1, pc = 1 - pp;  // h_l(t) lives in parity pc
    // X: L1(t) [A=h0(t)|h1(t-1)] + OUT(t-1)
    gates_tile<2048, false>(mb, nb, HBD(pc, 0), HBD(pp, 1), Wp1,
                            bias4all + 4096, nullptr, nullptr, nullptr, t,
                            HBD(pc, 1), h1r, smem);
    if (t > 0) out_tile(bid, HBD(pp, 2), owTv, logitde, out, t - 1, smem);
    gbar(flags, ++gen, dead);
    // Y: L2(t) [A=h1(t)|h2(t-1)] + L0(t+1) [A=h0(t)]
    gates_tile<2048, false>(mb, nb, HBD(pc, 1), HBD(pp, 2), Wp2,
                            bias4all + 8192, nullptr, nullptr, nullptr, t,
                            HBD(pc, 2), h2r, smem);
    if (t + 1 < S_)
      gates_tile<1024, true>(mb, nb, HBD(pc, 0), HBD(pc, 0), Wp0, bias4all,
                             table, gprec0, inputs, t + 1, HBD(pp, 0), h0r,
                             smem);
    gbar(flags, ++gen, dead);
  }
  // Epilogue: OUT(199); h2(199) parity = (199+1)&1 = 0.
  out_tile(bid, HBD(0, 2), owTv, logitde, out, S_ - 1, smem);
#undef HBD
}

// ---------------------------------------------------------------------------
// fp32 precompute GEMM: C[m][n] = sum_k A[m*lda+k]*W[n*ldw+woff+k] + bias[n]
// ---------------------------------------------------------------------------
__global__ __launch_bounds__(256) void pgemm(
    const float* __restrict__ A, int lda, const float* __restrict__ W, int ldw,
    int woff, const float* __restrict__ bias, float* __restrict__ C,
    int M, int N, int K)
{
  __shared__ float As[64][33];
  __shared__ float Ws[64][33];
  const int tid = threadIdx.x;
  const int tx = tid & 15, ty = tid >> 4;
  const int mb = blockIdx.x * 64, nb = blockIdx.y * 64;
  float acc[4][4];
#pragma unroll
  for (int i = 0; i < 4; ++i)
#pragma unroll
    for (int j = 0; j < 4; ++j) acc[i][j] = 0.f;

  for (int k0 = 0; k0 < K; k0 += 32) {
#pragma unroll
    for (int s = 0; s < 8; ++s) {
      int idx = s * 256 + tid;
      int r = idx >> 5, c = idx & 31;
      int m = mb + r;
      As[r][c] = (m < M) ? A[m * lda + k0 + c] : 0.f;
      int n = nb + r;
      Ws[r][c] = (n < N) ? W[n * ldw + woff + k0 + c] : 0.f;
    }
    __syncthreads();
#pragma unroll 8
    for (int kk = 0; kk < 32; ++kk) {
      float a[4], ww[4];
#pragma unroll
      for (int i = 0; i < 4; ++i) a[i] = As[ty * 4 + i][kk];
#pragma unroll
      for (int j = 0; j < 4; ++j) ww[j] = Ws[tx * 4 + j][kk];
#pragma unroll
      for (int i = 0; i < 4; ++i)
#pragma unroll
        for (int j = 0; j < 4; ++j) acc[i][j] += a[i] * ww[j];
    }
    __syncthreads();
  }
#pragma unroll
  for (int i = 0; i < 4; ++i) {
    int m = mb + ty * 4 + i;
    if (m >= M) continue;
#pragma unroll
    for (int j = 0; j < 4; ++j) {
      int n = nb + tx * 4 + j;
      if (n < N) C[m * N + n] = acc[i][j] + (bias ? bias[n] : 0.f);
    }
  }
}

// --------------------------- small pack kernels ----------------------------
__global__ void k_de(const float* __restrict__ z, const float* __restrict__ c,
                     float* __restrict__ de) {
  int i = blockIdx.x * 256 + threadIdx.x;  // 512*1024
  int b = i >> 10, q = i & 1023;
  de[i] = (q < 512) ? z[b * 512 + q] : c[b * 512 + (q - 512)];
}

__global__ void k_wpack(const float* __restrict__ wih,
                        const float* __restrict__ whh, bf16* __restrict__ Wp,
                        int ktshift) {
  int KT = 1 << ktshift;
  int i = blockIdx.x * 256 + threadIdx.x;
  if (i >= 3072 * KT) return;
  int k = i & (KT - 1);
  int row = i >> ktshift;  // g*1024 + n
  float v = (k < 1024) ? wih[row * 1024 + k] : whh[row * 1024 + (k - 1024)];
  Wp[i] = __float2bfloat16(v);
}

__global__ void k_bias4(const float* __restrict__ bih,
                        const float* __restrict__ bhh, float* __restrict__ dst,
                        int l0) {
  int n = blockIdx.x * 256 + threadIdx.x;
  if (n >= 1024) return;
  dst[n] = l0 ? bhh[n] : bih[n] + bhh[n];
  dst[1024 + n] = l0 ? bhh[1024 + n] : bih[1024 + n] + bhh[1024 + n];
  dst[2048 + n] = l0 ? 0.f : bih[2048 + n];
  dst[3072 + n] = bhh[2048 + n];
}

__global__ void k_owt(const float* __restrict__ out_w, bf16* __restrict__ owTv) {
  int i = blockIdx.x * 256 + threadIdx.x;  // 100*1024
  if (i >= V_ * H_) return;
  int v = i >> 10, k = i & 1023;
  owTv[i] = __float2bfloat16(out_w[v * 2048 + k]);
}

__global__ void k_hinit(const float* __restrict__ hinit, bf16* __restrict__ h0,
                        bf16* __restrict__ h1, bf16* __restrict__ h2) {
  int i = blockIdx.x * 256 + threadIdx.x;  // 512*1024
  bf16 v = __float2bfloat16(hinit[i]);
  h0[i] = v; h1[i] = v; h2[i] = v;
}

__global__ void k_zero(unsigned* __restrict__ p) {
  p[threadIdx.x] = 0u;
  p[256 + threadIdx.x] = 0u;
  p[512 + threadIdx.x] = 0u;
}

// ---------------------------------------------------------------------------
extern "C" void kernel_launch(void* const* d_in, const int* in_sizes, int n_in,
                              void* d_out, int out_size, void* d_ws,
                              size_t ws_size, hipStream_t stream) {
  const int* inputs = (const int*)d_in[0];
  const float* z = (const float*)d_in[1];
  const float* cond = (const float*)d_in[2];
  // d_in[3] = temperature (ignored: >=1 -> always teacher-forced)
  const float* emb = (const float*)d_in[4];
  const float* i2h_w = (const float*)d_in[5];
  const float* i2h_b = (const float*)d_in[6];
  const float* out_w = (const float*)d_in[7];
  const float* out_b = (const float*)d_in[8];
  const float* wih0 = (const float*)d_in[9];
  const float* whh0 = (const float*)d_in[10];
  const float* bih0 = (const float*)d_in[11];
  const float* bhh0 = (const float*)d_in[12];
  const float* wih1 = (const float*)d_in[13];
  const float* whh1 = (const float*)d_in[14];
  const float* bih1 = (const float*)d_in[15];
  const float* bhh1 = (const float*)d_in[16];
  const float* wih2 = (const float*)d_in[17];
  const float* whh2 = (const float*)d_in[18];
  const float* bih2 = (const float*)d_in[19];
  const float* bhh2 = (const float*)d_in[20];
  float* out = (float*)d_out;

  char* p = (char*)d_ws;
  float* de = (float*)(p + 0);                 //  2 MB
  float* gprec0 = (float*)(p + 2097152);       //  6.29 MB
  float* table = (float*)(p + 8388608);        //  1.23 MB
  float* hinit = (float*)(p + 9617408);        //  2 MB (dead after k_hinit)
  float* logitde = (float*)(p + 11714560);     //  0.2 MB
  float* bias4 = (float*)(p + 11919360);       //  48 KB [3][4][1024]
  bf16* Wp0 = (bf16*)(p + 11968512);           //  6.29 MB
  bf16* Wp1 = (bf16*)(p + 18259968);           // 12.58 MB
  bf16* Wp2 = (bf16*)(p + 30842880);           // 12.58 MB
  bf16* owTv = (bf16*)(p + 43425792);          //  0.2 MB
  bf16* hbuf = (bf16*)(p + 43630592);          //  6.29 MB [2][3][512][1024]
  unsigned* flags = (unsigned*)(p + 9617408);  // 3 KB, reuses dead hinit space

  // ---- one-time precompute (per call; weights re-restored each call) ----
  k_de<<<2048, 256, 0, stream>>>(z, cond, de);
  pgemm<<<dim3(8, 48), 256, 0, stream>>>(de, 1024, wih0, 1536, 512, bih0,
                                         gprec0, 512, 3072, 1024);
  pgemm<<<dim3(2, 48), 256, 0, stream>>>(emb, 512, wih0, 1536, 0, nullptr,
                                         table, 100, 3072, 512);
  pgemm<<<dim3(8, 16), 256, 0, stream>>>(de, 1024, i2h_w, 1024, 0, i2h_b,
                                         hinit, 512, 1024, 1024);
  pgemm<<<dim3(8, 2), 256, 0, stream>>>(de, 1024, out_w, 2048, 1024, out_b,
                                        logitde, 512, 100, 1024);
  k_bias4<<<4, 256, 0, stream>>>(bhh0, bhh0, bias4, 1);
  k_bias4<<<4, 256, 0, stream>>>(bih1, bhh1, bias4 + 4096, 0);
  k_bias4<<<4, 256, 0, stream>>>(bih2, bhh2, bias4 + 8192, 0);
  k_wpack<<<(3072 * 1024 + 255) / 256, 256, 0, stream>>>(whh0, whh0, Wp0, 10);
  k_wpack<<<(3072 * 2048 + 255) / 256, 256, 0, stream>>>(wih1, whh1, Wp1, 11);
  k_wpack<<<(3072 * 2048 + 255) / 256, 256, 0, stream>>>(wih2, whh2, Wp2, 11);
  k_owt<<<400, 256, 0, stream>>>(out_w, owTv);
#define HB(par, l) (hbuf + ((par) * 3 + (l)) * (B_ * H_))
  k_hinit<<<2048, 256, 0, stream>>>(hinit, HB(0, 0), HB(0, 1), HB(0, 2));
#undef HB
  k_zero<<<1, 256, 0, stream>>>(flags);  // after k_hinit (flags alias hinit)

  // ---- entire 200-step scan: one persistent kernel, 2 blocks/CU ----
  scan_kernel<<<NBLK, 256, 0, stream>>>(inputs, Wp0, Wp1, Wp2, bias4, table,
                                        gprec0, owTv, logitde, hbuf, out,
                                        flags);
}